// Round 1
// 162.627 us; speedup vs baseline: 1.0140x; 1.0140x over previous
//
#include <hip/hip_runtime.h>

#define N_NODES 20000
#define N_EDGES 640000
#define D 128
#define CAP 128   // bucket capacity per node (P(deg>128) ~ 0 for Poisson(32))

typedef __attribute__((ext_vector_type(8))) short bf16x8;
typedef __attribute__((ext_vector_type(4))) float f32x4;

__device__ __forceinline__ short f2bf(float f) {
    union { float f; unsigned u; } un; un.f = f;
    unsigned r = un.u + 0x7fff + ((un.u >> 16) & 1);
    return (short)(r >> 16);
}
__device__ __forceinline__ float bflo(unsigned u) { return __uint_as_float(u << 16); }
__device__ __forceinline__ float bfhi(unsigned u) { return __uint_as_float(u & 0xffff0000u); }

// ---------------------------------------------------------------------------
// Fused prep:
//   blocks [0,2500):    fill buckets — 1 edge/thread for max TLP (latency-bound
//                       atomic+scatter chains; was 4 edges/thread = 2.4 waves/SIMD)
//   blocks [2500,5000): convert x -> bf16
//   blocks [5000,5032): pack W1/W2 into MFMA B-fragment layout
// ---------------------------------------------------------------------------
__global__ __launch_bounds__(256) void prep_kernel(
    const float* __restrict__ x,
    const int* __restrict__ src, const int* __restrict__ dst,
    const float* __restrict__ W1_rel, const float* __restrict__ W1_root,
    const float* __restrict__ W2_rel, const float* __restrict__ W2_root,
    int* __restrict__ cnt, unsigned short* __restrict__ buckets,
    short* __restrict__ xb, short* __restrict__ wpk1, short* __restrict__ wpk2)
{
    const int b = blockIdx.x;
    const int tid = threadIdx.x;
    if (b < 2500) {
        int e = b * 256 + tid;               // one edge per thread: single
        int d = dst[e];                      // atomic->store chain, 10K waves
        int s = src[e];                      // in flight instead of 2.5K x 4-deep
        int p = atomicAdd(&cnt[d], 1);
        if (p < CAP) buckets[(d << 7) + p] = (unsigned short)s;
    } else if (b < 5000) {
        int i = (b - 2500) * 256 + tid;
        float4 v = ((const float4*)x)[i];
        ushort4 o;
        o.x = (unsigned short)f2bf(v.x);
        o.y = (unsigned short)f2bf(v.y);
        o.z = (unsigned short)f2bf(v.z);
        o.w = (unsigned short)f2bf(v.w);
        ((ushort4*)xb)[i] = o;
    } else {
        int pb  = b - 5000;
        int job = pb >> 4;                   // 0 -> layer1, 1 -> layer2
        int idx = (pb & 15) * 256 + tid;     // 0..4095
        const float* Wrel  = job ? W2_rel  : W1_rel;
        const float* Wroot = job ? W2_root : W1_root;
        short* Wpk = job ? wpk2 : wpk1;
        int lane = idx & 63;
        int ct   = (idx >> 6) & 7;
        int t    = idx >> 9;
        const float* W = (t < 4) ? Wrel : Wroot;
        int k0  = (t & 3) * 32 + (lane >> 4) * 8;
        int col = ct * 16 + (lane & 15);
        bf16x8 pk;
#pragma unroll
        for (int j = 0; j < 8; j++)
            pk[j] = f2bf(W[(size_t)(k0 + j) * D + col]);
        ((bf16x8*)Wpk)[idx] = pk;
    }
}

// ---------------------------------------------------------------------------
// Fused layer: out = [relu]( agg @ Wrel + b + x @ Wroot ), virtual K=256 GEMM.
// 512 threads, 16 nodes/block, 1250 blocks.
// Phase 1 (gather): half-wave per node, whole bucket as uint2/lane + shfl
//   broadcast -> 8 independent 256B row-gathers in flight; agg row -> LDS bf16.
// Phase 2 (MFMA): wave w = col-tile w; A-frags: LDS (agg) + global (x rows);
//   B-frags: packed Wpk (L2-hot).
// ---------------------------------------------------------------------------
template <bool RELU, bool OUT_BF16>
__global__ __launch_bounds__(512) void layer_kernel(
    const short* __restrict__ xin,
    const int* __restrict__ cnt,
    const unsigned short* __restrict__ buckets,
    const short* __restrict__ Wpk,
    const float* __restrict__ brel,
    void* __restrict__ outp)
{
    __shared__ short sAgg[16][136];   // stride 272B: 16B-aligned rows, 2-way banks

    const int tid  = threadIdx.x;
    const int row0 = blockIdx.x * 16;

    // ---- phase 1: gather-aggregate into LDS ----
    {
        const int hw   = tid >> 5;       // 0..15 -> node
        const int lane = tid & 31;
        const int node = row0 + hw;
        int n = cnt[node];
        n = (n > CAP) ? CAP : n;
        uint2 idxpk = *(const uint2*)(buckets + (node << 7) + lane * 4);

        float4 acc = make_float4(0.f, 0.f, 0.f, 0.f);
        int i = 0;
        for (; i + 8 <= n; i += 8) {
            int baseLane = i >> 2;
            uint2 u[8];
#pragma unroll
            for (int q = 0; q < 8; q++) {
                unsigned word = __shfl((q & 2) ? idxpk.y : idxpk.x,
                                       baseLane + (q >> 2), 32);
                unsigned sidx = (q & 1) ? (word >> 16) : (word & 0xffffu);
                u[q] = *(const uint2*)(xin + (size_t)sidx * D + lane * 4);
            }
#pragma unroll
            for (int q = 0; q < 8; q++) {
                acc.x += bflo(u[q].x); acc.y += bfhi(u[q].x);
                acc.z += bflo(u[q].y); acc.w += bfhi(u[q].y);
            }
        }
        for (; i < n; i++) {
            unsigned word = __shfl((i & 2) ? idxpk.y : idxpk.x, i >> 2, 32);
            unsigned sidx = (i & 1) ? (word >> 16) : (word & 0xffffu);
            uint2 u0 = *(const uint2*)(xin + (size_t)sidx * D + lane * 4);
            acc.x += bflo(u0.x); acc.y += bfhi(u0.x);
            acc.z += bflo(u0.y); acc.w += bfhi(u0.y);
        }
        ushort4 o;
        o.x = (unsigned short)f2bf(acc.x);
        o.y = (unsigned short)f2bf(acc.y);
        o.z = (unsigned short)f2bf(acc.z);
        o.w = (unsigned short)f2bf(acc.w);
        *(ushort4*)&sAgg[hw][lane * 4] = o;
    }
    __syncthreads();

    // ---- phase 2: MFMA, wave = one 16-col tile ----
    const int wave = tid >> 6;          // 0..7
    const int lane = tid & 63;
    const int quad = lane >> 4;
    const int l16  = lane & 15;

    f32x4 acc = (f32x4){0.f, 0.f, 0.f, 0.f};
    const short* arow_x = xin + (size_t)(row0 + l16) * D + quad * 8;
    const bf16x8* wb = (const bf16x8*)Wpk + lane;

#pragma unroll
    for (int t = 0; t < 8; t++) {
        bf16x8 a;
        if (t < 4)
            a = *(const bf16x8*)&sAgg[l16][(t & 3) * 32 + quad * 8];
        else
            a = *(const bf16x8*)(arow_x + (t & 3) * 32);
        bf16x8 bfr = wb[(t * 8 + wave) * 64];
        acc = __builtin_amdgcn_mfma_f32_16x16x32_bf16(a, bfr, acc, 0, 0, 0);
    }

    const int col  = wave * 16 + l16;
    const int orow = row0 + quad * 4;
    const float bias = brel[col];
#pragma unroll
    for (int r = 0; r < 4; r++) {
        float v = acc[r] + bias;
        if (RELU) v = fmaxf(v, 0.f);
        if (OUT_BF16)
            ((short*)outp)[(size_t)(orow + r) * D + col] = f2bf(v);
        else
            ((float*)outp)[(size_t)(orow + r) * D + col] = v;
    }
}

// ---------------------------------------------------------------------------
extern "C" void kernel_launch(void* const* d_in, const int* in_sizes, int n_in,
                              void* d_out, int out_size, void* d_ws, size_t ws_size,
                              hipStream_t stream) {
    const float* x       = (const float*)d_in[0];
    const int*   ei      = (const int*)  d_in[1];
    const float* W1_rel  = (const float*)d_in[2];
    const float* b1_rel  = (const float*)d_in[3];
    const float* W1_root = (const float*)d_in[4];
    const float* W2_rel  = (const float*)d_in[5];
    const float* b2_rel  = (const float*)d_in[6];
    const float* W2_root = (const float*)d_in[7];
    float* out = (float*)d_out;

    // ws layout (16B-aligned blocks)
    char* p = (char*)d_ws;
    short* xb   = (short*)p;  p += (size_t)N_NODES * D * 2;   // 5.12 MB
    short* hb   = (short*)p;  p += (size_t)N_NODES * D * 2;   // 5.12 MB
    short* wpk1 = (short*)p;  p += 65536;                     // 64 KB
    short* wpk2 = (short*)p;  p += 65536;                     // 64 KB
    int*   cnt  = (int*)p;    p += (size_t)N_NODES * 4;       // 80 KB
    unsigned short* buckets = (unsigned short*)p;             // 5.12 MB

    const int* src = ei;
    const int* dst = ei + N_EDGES;

    const int layerblocks = N_NODES / 16;   // 1250

    // ---- prep: zero counters, then fused fill+convert+pack ----
    hipMemsetAsync(cnt, 0, (size_t)N_NODES * sizeof(int), stream);
    prep_kernel<<<5032, 256, 0, stream>>>(
        x, src, dst, W1_rel, W1_root, W2_rel, W2_root,
        cnt, buckets, xb, wpk1, wpk2);

    // ---- layer 1 (x -> hb, bf16, relu) ----
    layer_kernel<true, true><<<layerblocks, 512, 0, stream>>>(
        xb, cnt, buckets, wpk1, b1_rel, (void*)hb);

    // ---- layer 2 (hb -> out, fp32) ----
    layer_kernel<false, false><<<layerblocks, 512, 0, stream>>>(
        hb, cnt, buckets, wpk2, b2_rel, (void*)out);
}

// Round 2
// 149.934 us; speedup vs baseline: 1.0998x; 1.0847x over previous
//
#include <hip/hip_runtime.h>

#define N_NODES 20000
#define N_EDGES 640000
#define D 128
#define CAP 128      // bucket capacity per node (P(deg>128) ~ 0 for Poisson(32))
#define NBINS 157    // ceil(20000/128) nodes per bin = 128
#define BINCAP 4608  // expected 4096/bin, sigma~64 -> 8-sigma margin

typedef __attribute__((ext_vector_type(8))) short bf16x8;
typedef __attribute__((ext_vector_type(4))) float f32x4;

__device__ __forceinline__ short f2bf(float f) {
    union { float f; unsigned u; } un; un.f = f;
    unsigned r = un.u + 0x7fff + ((un.u >> 16) & 1);
    return (short)(r >> 16);
}
__device__ __forceinline__ float bflo(unsigned u) { return __uint_as_float(u << 16); }
__device__ __forceinline__ float bfhi(unsigned u) { return __uint_as_float(u & 0xffff0000u); }

// ---------------------------------------------------------------------------
// Fused prep:
//   blocks [0,256):     pass A — bin edges by dst>>7 into per-bin chunks.
//                       LDS histogram + ONE global atomic per (block,bin)
//                       (40K device atomics instead of 640K; chunk writes
//                       are sequential -> no 64B write amplification)
//   blocks [256,2756):  convert x -> bf16
//   blocks [2756,2788): pack W1/W2 into MFMA B-fragment layout
// ---------------------------------------------------------------------------
__global__ __launch_bounds__(256) void prep_kernel(
    const float* __restrict__ x,
    const int* __restrict__ src, const int* __restrict__ dst,
    const float* __restrict__ W1_rel, const float* __restrict__ W1_root,
    const float* __restrict__ W2_rel, const float* __restrict__ W2_root,
    int* __restrict__ binCursor, unsigned* __restrict__ binned,
    short* __restrict__ xb, short* __restrict__ wpk1, short* __restrict__ wpk2)
{
    const int b = blockIdx.x;
    const int tid = threadIdx.x;
    if (b < 256) {
        __shared__ int hist[NBINS];
        __shared__ int sBase[NBINS];
        __shared__ int sOff[NBINS];
        for (int i = tid; i < NBINS; i += 256) { hist[i] = 0; sOff[i] = 0; }
        __syncthreads();
        const int e0 = b * 2500;          // 256 * 2500 = 640000 exactly
        int d[10], s[10];
#pragma unroll
        for (int k = 0; k < 10; k++) {
            int idx = k * 256 + tid;
            if (idx < 2500) {
                d[k] = dst[e0 + idx];
                s[k] = src[e0 + idx];
                atomicAdd(&hist[d[k] >> 7], 1);
            } else {
                d[k] = -1;
            }
        }
        __syncthreads();
        for (int i = tid; i < NBINS; i += 256)
            sBase[i] = atomicAdd(&binCursor[i], hist[i]);
        __syncthreads();
#pragma unroll
        for (int k = 0; k < 10; k++) {
            if (d[k] >= 0) {
                int bin = d[k] >> 7;
                int off = sBase[bin] + atomicAdd(&sOff[bin], 1);
                if (off < BINCAP)
                    binned[bin * BINCAP + off] =
                        ((unsigned)(d[k] & 127) << 16) | (unsigned)s[k];
            }
        }
    } else if (b < 2756) {
        int i = (b - 256) * 256 + tid;
        float4 v = ((const float4*)x)[i];
        ushort4 o;
        o.x = (unsigned short)f2bf(v.x);
        o.y = (unsigned short)f2bf(v.y);
        o.z = (unsigned short)f2bf(v.z);
        o.w = (unsigned short)f2bf(v.w);
        ((ushort4*)xb)[i] = o;
    } else {
        int pb  = b - 2756;
        int job = pb >> 4;                   // 0 -> layer1, 1 -> layer2
        int idx = (pb & 15) * 256 + tid;     // 0..4095
        const float* Wrel  = job ? W2_rel  : W1_rel;
        const float* Wroot = job ? W2_root : W1_root;
        short* Wpk = job ? wpk2 : wpk1;
        int lane = idx & 63;
        int ct   = (idx >> 6) & 7;
        int t    = idx >> 9;
        const float* W = (t < 4) ? Wrel : Wroot;
        int k0  = (t & 3) * 32 + (lane >> 4) * 8;
        int col = ct * 16 + (lane & 15);
        bf16x8 pk;
#pragma unroll
        for (int j = 0; j < 8; j++)
            pk[j] = f2bf(W[(size_t)(k0 + j) * D + col]);
        ((bf16x8*)Wpk)[idx] = pk;
    }
}

// ---------------------------------------------------------------------------
// Pass B: one block per bin. LDS per-node counters (LDS atomics, not device),
// scatter srcs into node buckets (stores stay within a 32KB window -> L2-local),
// emit cnt[] from the LDS counters. Zero device-scope atomics.
// ---------------------------------------------------------------------------
__global__ __launch_bounds__(256) void binplace_kernel(
    const unsigned* __restrict__ binned, const int* __restrict__ binCursor,
    unsigned short* __restrict__ buckets, int* __restrict__ cnt)
{
    __shared__ int lcnt[128];
    const int bin = blockIdx.x;
    const int tid = threadIdx.x;
    if (tid < 128) lcnt[tid] = 0;
    __syncthreads();
    int n = binCursor[bin];
    if (n > BINCAP) n = BINCAP;
    const unsigned* rec = binned + bin * BINCAP;
    for (int i = tid; i < n; i += 256) {
        unsigned u = rec[i];
        int nl = (int)(u >> 16);
        int slot = atomicAdd(&lcnt[nl], 1);     // LDS atomic
        if (slot < CAP)
            buckets[(((bin << 7) | nl) << 7) + slot] = (unsigned short)(u & 0xffffu);
    }
    __syncthreads();
    int node = (bin << 7) + tid;
    if (tid < 128 && node < N_NODES) cnt[node] = lcnt[tid];
}

// ---------------------------------------------------------------------------
// Fused layer: out = [relu]( agg @ Wrel + b + x @ Wroot ), virtual K=256 GEMM.
// (unchanged this round)
// ---------------------------------------------------------------------------
template <bool RELU, bool OUT_BF16>
__global__ __launch_bounds__(512) void layer_kernel(
    const short* __restrict__ xin,
    const int* __restrict__ cnt,
    const unsigned short* __restrict__ buckets,
    const short* __restrict__ Wpk,
    const float* __restrict__ brel,
    void* __restrict__ outp)
{
    __shared__ short sAgg[16][136];   // stride 272B: 16B-aligned rows, 2-way banks

    const int tid  = threadIdx.x;
    const int row0 = blockIdx.x * 16;

    // ---- phase 1: gather-aggregate into LDS ----
    {
        const int hw   = tid >> 5;       // 0..15 -> node
        const int lane = tid & 31;
        const int node = row0 + hw;
        int n = cnt[node];
        n = (n > CAP) ? CAP : n;
        uint2 idxpk = *(const uint2*)(buckets + (node << 7) + lane * 4);

        float4 acc = make_float4(0.f, 0.f, 0.f, 0.f);
        int i = 0;
        for (; i + 8 <= n; i += 8) {
            int baseLane = i >> 2;
            uint2 u[8];
#pragma unroll
            for (int q = 0; q < 8; q++) {
                unsigned word = __shfl((q & 2) ? idxpk.y : idxpk.x,
                                       baseLane + (q >> 2), 32);
                unsigned sidx = (q & 1) ? (word >> 16) : (word & 0xffffu);
                u[q] = *(const uint2*)(xin + (size_t)sidx * D + lane * 4);
            }
#pragma unroll
            for (int q = 0; q < 8; q++) {
                acc.x += bflo(u[q].x); acc.y += bfhi(u[q].x);
                acc.z += bflo(u[q].y); acc.w += bfhi(u[q].y);
            }
        }
        for (; i < n; i++) {
            unsigned word = __shfl((i & 2) ? idxpk.y : idxpk.x, i >> 2, 32);
            unsigned sidx = (i & 1) ? (word >> 16) : (word & 0xffffu);
            uint2 u0 = *(const uint2*)(xin + (size_t)sidx * D + lane * 4);
            acc.x += bflo(u0.x); acc.y += bfhi(u0.x);
            acc.z += bflo(u0.y); acc.w += bfhi(u0.y);
        }
        ushort4 o;
        o.x = (unsigned short)f2bf(acc.x);
        o.y = (unsigned short)f2bf(acc.y);
        o.z = (unsigned short)f2bf(acc.z);
        o.w = (unsigned short)f2bf(acc.w);
        *(ushort4*)&sAgg[hw][lane * 4] = o;
    }
    __syncthreads();

    // ---- phase 2: MFMA, wave = one 16-col tile ----
    const int wave = tid >> 6;          // 0..7
    const int lane = tid & 63;
    const int quad = lane >> 4;
    const int l16  = lane & 15;

    f32x4 acc = (f32x4){0.f, 0.f, 0.f, 0.f};
    const short* arow_x = xin + (size_t)(row0 + l16) * D + quad * 8;
    const bf16x8* wb = (const bf16x8*)Wpk + lane;

#pragma unroll
    for (int t = 0; t < 8; t++) {
        bf16x8 a;
        if (t < 4)
            a = *(const bf16x8*)&sAgg[l16][(t & 3) * 32 + quad * 8];
        else
            a = *(const bf16x8*)(arow_x + (t & 3) * 32);
        bf16x8 bfr = wb[(t * 8 + wave) * 64];
        acc = __builtin_amdgcn_mfma_f32_16x16x32_bf16(a, bfr, acc, 0, 0, 0);
    }

    const int col  = wave * 16 + l16;
    const int orow = row0 + quad * 4;
    const float bias = brel[col];
#pragma unroll
    for (int r = 0; r < 4; r++) {
        float v = acc[r] + bias;
        if (RELU) v = fmaxf(v, 0.f);
        if (OUT_BF16)
            ((short*)outp)[(size_t)(orow + r) * D + col] = f2bf(v);
        else
            ((float*)outp)[(size_t)(orow + r) * D + col] = v;
    }
}

// ---------------------------------------------------------------------------
extern "C" void kernel_launch(void* const* d_in, const int* in_sizes, int n_in,
                              void* d_out, int out_size, void* d_ws, size_t ws_size,
                              hipStream_t stream) {
    const float* x       = (const float*)d_in[0];
    const int*   ei      = (const int*)  d_in[1];
    const float* W1_rel  = (const float*)d_in[2];
    const float* b1_rel  = (const float*)d_in[3];
    const float* W1_root = (const float*)d_in[4];
    const float* W2_rel  = (const float*)d_in[5];
    const float* b2_rel  = (const float*)d_in[6];
    const float* W2_root = (const float*)d_in[7];
    float* out = (float*)d_out;

    // ws layout (16B-aligned blocks)
    char* p = (char*)d_ws;
    short* xb   = (short*)p;  p += (size_t)N_NODES * D * 2;        // 5.12 MB
    short* hb   = (short*)p;  p += (size_t)N_NODES * D * 2;        // 5.12 MB
    short* wpk1 = (short*)p;  p += 65536;                          // 64 KB
    short* wpk2 = (short*)p;  p += 65536;                          // 64 KB
    int*   cnt  = (int*)p;    p += (size_t)N_NODES * 4;            // 80 KB
    unsigned short* buckets = (unsigned short*)p;
    p += (size_t)N_NODES * CAP * 2;                                // 5.12 MB
    unsigned* binned = (unsigned*)p;
    p += (size_t)NBINS * BINCAP * 4;                               // 2.89 MB
    int* binCursor = (int*)p;                                      // 628 B

    const int* src = ei;
    const int* dst = ei + N_EDGES;

    const int layerblocks = N_NODES / 16;   // 1250

    // ---- prep: zero bin cursors, then fused bin+convert+pack ----
    hipMemsetAsync(binCursor, 0, (size_t)NBINS * sizeof(int), stream);
    prep_kernel<<<2788, 256, 0, stream>>>(
        x, src, dst, W1_rel, W1_root, W2_rel, W2_root,
        binCursor, binned, xb, wpk1, wpk2);

    // ---- pass B: per-bin LDS-atomic placement into buckets + cnt ----
    binplace_kernel<<<NBINS, 256, 0, stream>>>(binned, binCursor, buckets, cnt);

    // ---- layer 1 (x -> hb, bf16, relu) ----
    layer_kernel<true, true><<<layerblocks, 512, 0, stream>>>(
        xb, cnt, buckets, wpk1, b1_rel, (void*)hb);

    // ---- layer 2 (hb -> out, fp32) ----
    layer_kernel<false, false><<<layerblocks, 512, 0, stream>>>(
        hb, cnt, buckets, wpk2, b2_rel, (void*)out);
}